// Round 10
// baseline (298.869 us; speedup 1.0000x reference)
//
#include <hip/hip_runtime.h>
#include <math.h>

#define NA 50000
#define NE 800000
#define FDIM 128
#define KDIM 64
#define NRI 3
#define NRA 2

typedef unsigned short ushort_t;
typedef unsigned int uint_t;
typedef __attribute__((ext_vector_type(8))) short short8v;
typedef __attribute__((ext_vector_type(4))) float f32x4;
typedef __attribute__((ext_vector_type(4))) unsigned short u16x4;

// ssp(x) = softplus(x) - ln2 via hardware v_exp_f32/v_log_f32.
__device__ __forceinline__ float ssp_f(float x) {
    float e = __expf(-fabsf(x));
    return fmaxf(x, 0.0f) + __logf(1.0f + e) - 0.69314718055994530942f;
}
__device__ __forceinline__ ushort_t f2bf(float x) {
    unsigned u = __float_as_uint(x);
    u += 0x7FFFu + ((u >> 16) & 1u);          // RNE
    return (ushort_t)(u >> 16);
}
__device__ __forceinline__ float bf2f(ushort_t h) {
    return __uint_as_float(((unsigned)h) << 16);
}
__device__ __forceinline__ f32x4 ssp4(f32x4 v) {
    f32x4 r;
    #pragma unroll
    for (int j = 0; j < 4; ++j) r[j] = ssp_f(v[j]);
    return r;
}
__device__ __forceinline__ u16x4 pack4(f32x4 v) {
    u16x4 p;
    #pragma unroll
    for (int j = 0; j < 4; ++j) p[j] = f2bf(v[j]);
    return p;
}

// ---------------------------------------------------------------------------
// Weight pre-convert (once): fp32 -> bf16 into ws.
// wbf layout (ushort offsets): Wdesc@0 (8192), Wi@8192, Wj@24576,
// chain@40960: [Wri1_0,Wri2_0,Wri1_1,Wri2_1,Wri1_2,Wri2_2,Wd,Wra1_0,Wra2_0,Wra1_1,Wra2_1]
// ---------------------------------------------------------------------------
__global__ __launch_bounds__(256) void k_wconv(
    const float* __restrict__ Wdesc, const float* __restrict__ Wi,
    const float* __restrict__ Wj,    const float* __restrict__ Wri1,
    const float* __restrict__ Wri2,  const float* __restrict__ Wd,
    const float* __restrict__ Wra1,  const float* __restrict__ Wra2,
    ushort_t* __restrict__ wbf)
{
    const int seg = blockIdx.y;
    const int idx = blockIdx.x * 2048 + threadIdx.x * 8;
    const float* s; ushort_t* d; int cnt;
    const int CH = 40960;
    switch (seg) {
    case 0: cnt = 8192;  if (idx >= cnt) return; s = Wdesc + idx; d = wbf + idx; break;
    case 1: cnt = 16384; if (idx >= cnt) return; s = Wi + idx;    d = wbf + 8192 + idx; break;
    case 2: cnt = 16384; if (idx >= cnt) return; s = Wj + idx;    d = wbf + 24576 + idx; break;
    case 3: { cnt = 3*16384; if (idx >= cnt) return; int k = idx/16384, o = idx - k*16384;
              s = Wri1 + idx; d = wbf + CH + (2*k)*16384 + o; break; }
    case 4: { cnt = 3*16384; if (idx >= cnt) return; int k = idx/16384, o = idx - k*16384;
              s = Wri2 + idx; d = wbf + CH + (2*k+1)*16384 + o; break; }
    case 5: cnt = 16384; if (idx >= cnt) return; s = Wd + idx; d = wbf + CH + 6*16384 + idx; break;
    case 6: { cnt = 2*16384; if (idx >= cnt) return; int k = idx/16384, o = idx - k*16384;
              s = Wra1 + idx; d = wbf + CH + (7+2*k)*16384 + o; break; }
    default:{ cnt = 2*16384; if (idx >= cnt) return; int k = idx/16384, o = idx - k*16384;
              s = Wra2 + idx; d = wbf + CH + (8+2*k)*16384 + o; break; }
    }
    #pragma unroll
    for (int j = 0; j < 8; ++j) d[j] = f2bf(s[j]);
}

// ---------------------------------------------------------------------------
// Transposed-GEMM helpers. Wave w owns atoms {16w + lrow}; each lane holds
// features {16nf + 4kgrp + r} of its atom. C[row=W-row(feature)][col=act-row(atom)].
// ---------------------------------------------------------------------------
__device__ __forceinline__ void stage_w(const ushort_t* __restrict__ src,
                                        ushort_t (*wlds)[136], int t)
{
    const int r = t >> 1, c0 = (t & 1) * 64;
    const short8v* s = (const short8v*)(src + (size_t)r * FDIM + c0);
    #pragma unroll
    for (int q = 0; q < 8; ++q)
        *(short8v*)&wlds[r][c0 + q * 8] = s[q];
}

__device__ __forceinline__ void gemm_tile_T(
    const ushort_t (*actA)[136], const ushort_t (*wlds)[136],
    int w, int lrow, int kgrp, const float* __restrict__ bias, f32x4 acc[8])
{
    short8v bfr[4];
    #pragma unroll
    for (int ks = 0; ks < 4; ++ks)
        bfr[ks] = *(const short8v*)&actA[16 * w + lrow][ks * 32 + kgrp * 8];
    #pragma unroll
    for (int nf = 0; nf < 8; ++nf)
        acc[nf] = *(const f32x4*)(bias + 16 * nf + 4 * kgrp);
    #pragma unroll
    for (int nf = 0; nf < 8; ++nf)
        #pragma unroll
        for (int ks = 0; ks < 4; ++ks) {
            short8v av = *(const short8v*)&wlds[16 * nf + lrow][ks * 32 + kgrp * 8];
            acc[nf] = __builtin_amdgcn_mfma_f32_16x16x32_bf16(av, bfr[ks], acc[nf], 0, 0, 0);
        }
}

// act = ssp(v), packed b64 writes into this wave's own 16 rows
__device__ __forceinline__ void write_act_T(
    ushort_t (*actA)[136], int w, int lrow, int kgrp, const f32x4 v[8])
{
    #pragma unroll
    for (int nf = 0; nf < 8; ++nf)
        *(u16x4*)&actA[16 * w + lrow][16 * nf + 4 * kgrp] = pack4(ssp4(v[nf]));
}

// ---------------------------------------------------------------------------
// Node pre (MFMA, transposed): xi = ssp(ssp(feat)@Wi.T+bi) -> msg (f32)
//                              xja = ssp(ssp(feat)@Wj.T+bj) -> bf16
// ---------------------------------------------------------------------------
__global__ __launch_bounds__(256) void k_node_pre(
    const float* __restrict__ feat, const ushort_t* __restrict__ wbf,
    const float* __restrict__ bi, const float* __restrict__ bj,
    float* __restrict__ xi_out, ushort_t* __restrict__ xja_out)
{
    __shared__ ushort_t actA[64][136];
    __shared__ ushort_t wlds[128][136];
    const int t = threadIdx.x, lane = t & 63, w = t >> 6;
    const int lrow = lane & 15, kgrp = lane >> 4;
    const int atom = blockIdx.x * 64 + 16 * w + lrow;
    const bool ok = atom < NA;

    f32x4 v[8];
    #pragma unroll
    for (int nf = 0; nf < 8; ++nf)
        v[nf] = ok ? *(const f32x4*)(feat + (size_t)atom * FDIM + 16 * nf + 4 * kgrp)
                   : (f32x4){0.f, 0.f, 0.f, 0.f};
    write_act_T(actA, w, lrow, kgrp, v);
    __syncthreads();
    stage_w(wbf + 8192, wlds, t);
    __syncthreads();
    f32x4 acc[8];
    gemm_tile_T(actA, wlds, w, lrow, kgrp, bi, acc);
    if (ok)
        #pragma unroll
        for (int nf = 0; nf < 8; ++nf)
            *(f32x4*)(xi_out + (size_t)atom * FDIM + 16 * nf + 4 * kgrp) = ssp4(acc[nf]);
    __syncthreads();
    stage_w(wbf + 24576, wlds, t);
    __syncthreads();
    gemm_tile_T(actA, wlds, w, lrow, kgrp, bj, acc);
    if (ok)
        #pragma unroll
        for (int nf = 0; nf < 8; ++nf)
            *(u16x4*)(xja_out + (size_t)atom * FDIM + 16 * nf + 4 * kgrp) = pack4(ssp4(acc[nf]));
}

// ---------------------------------------------------------------------------
// Fused edge kernel: per block of 64 contiguous edges,
//   p[e][f] = (desc[e]@Wdesc[f]) * xja[idx_j[e]][f]   (MFMA, bf16 in LDS)
// then feature-parallel segmented sum over the 64 rows (idx_i sorted ->
// contiguous runs), flushed with native f32 atomics into msg.
// bf16 p-tile keeps LDS at 17.9 KB -> up to 8 blocks/CU (occupancy lever).
// ---------------------------------------------------------------------------
__device__ __forceinline__ short8v pack8(const float* p) {
    short8v r;
    #pragma unroll
    for (int j = 0; j < 8; ++j) r[j] = (short)f2bf(p[j]);
    return r;
}

__global__ __launch_bounds__(256, 8) void k_edge_fused(
    const float* __restrict__ desc, const ushort_t* __restrict__ wdbf,
    const int* __restrict__ idx_i, const int* __restrict__ idx_j,
    const ushort_t* __restrict__ xja,
    float* __restrict__ msg)
{
    __shared__ ushort_t pl[64][136];   // bf16 p tile (17.4 KB)
    __shared__ int ii[64];
    const int t = threadIdx.x, lane = t & 63, w = t >> 6;
    const int lrow = lane & 15, kgrp = lane >> 4;
    const int e0 = blockIdx.x * 64;
    const int er = e0 + w * 16 + lrow;          // this lane's edge (64 | NE)

    // longest chains first: idx_j (heads gather chain), then desc (HBM)
    const int jj = idx_j[er];
    const float* q = desc + (size_t)er * KDIM + kgrp * 8;
    float t0[8], t1[8];
    *(float4*)(t0)     = *(const float4*)q;
    *(float4*)(t0 + 4) = *(const float4*)(q + 4);
    *(float4*)(t1)     = *(const float4*)(q + 32);
    *(float4*)(t1 + 4) = *(const float4*)(q + 36);

    if (t < 64) ii[t] = idx_i[e0 + t];

    // Wdesc A-fragments (bf16, L2-hot)
    short8v a[8][2];
    #pragma unroll
    for (int nf = 0; nf < 8; ++nf)
        #pragma unroll
        for (int ks = 0; ks < 2; ++ks)
            a[nf][ks] = *(const short8v*)(wdbf + (size_t)(16 * nf + lrow) * KDIM
                                          + ks * 32 + kgrp * 8);

    short8v b0 = pack8(t0), b1 = pack8(t1);

    f32x4 acc[8];
    #pragma unroll
    for (int nf = 0; nf < 8; ++nf) acc[nf] = (f32x4){0.f, 0.f, 0.f, 0.f};
    #pragma unroll
    for (int nf = 0; nf < 8; ++nf) {
        acc[nf] = __builtin_amdgcn_mfma_f32_16x16x32_bf16(a[nf][0], b0, acc[nf], 0,0,0);
        acc[nf] = __builtin_amdgcn_mfma_f32_16x16x32_bf16(a[nf][1], b1, acc[nf], 0,0,0);
    }

    // gather-multiply, park in LDS as bf16
    #pragma unroll
    for (int nf = 0; nf < 8; ++nf) {
        u16x4 xv = *(const u16x4*)(xja + (size_t)jj * FDIM + 16 * nf + 4 * kgrp);
        f32x4 pr;
        #pragma unroll
        for (int j = 0; j < 4; ++j) pr[j] = acc[nf][j] * bf2f(xv[j]);
        *(u16x4*)&pl[w * 16 + lrow][16 * nf + 4 * kgrp] = pack4(pr);
    }
    __syncthreads();

    // segmented flush: thread = (feature, half); walk 32 rows, atomically add
    // each segment partial. idx_i sorted -> runs are contiguous.
    const int f = t & 127, h = t >> 7;
    const int r0 = h * 32, r1 = r0 + 32;
    float s = 0.0f;
    int cur = ii[r0];
    for (int r = r0; r < r1; ++r) {
        int id = ii[r];
        if (id != cur) {
            unsafeAtomicAdd(&msg[(size_t)cur * FDIM + f], s);
            s = 0.0f; cur = id;
        }
        s += bf2f(pl[r][f]);
    }
    unsafeAtomicAdd(&msg[(size_t)cur * FDIM + f], s);
}

// ---------------------------------------------------------------------------
// Fused node chain (transposed): 3 residuals + outmix + 2 residuals.
// m carried as f32x4[8] per thread (atom fixed per lane, features packed).
// ---------------------------------------------------------------------------
__global__ __launch_bounds__(256) void k_chain(
    const float* __restrict__ msgp, const float* __restrict__ feat,
    const float* __restrict__ u, const ushort_t* __restrict__ wch,
    const float* __restrict__ bri1, const float* __restrict__ bri2,
    const float* __restrict__ bd,
    const float* __restrict__ bra1, const float* __restrict__ bra2,
    float* __restrict__ xout)
{
    __shared__ ushort_t actA[64][136];
    __shared__ ushort_t wlds[128][136];
    const int t = threadIdx.x, lane = t & 63, w = t >> 6;
    const int lrow = lane & 15, kgrp = lane >> 4;
    const int atom = blockIdx.x * 64 + 16 * w + lrow;
    const bool ok = atom < NA;

    f32x4 m[8], h[8], acc[8];
    #pragma unroll
    for (int nf = 0; nf < 8; ++nf)
        m[nf] = ok ? *(const f32x4*)(msgp + (size_t)atom * FDIM + 16 * nf + 4 * kgrp)
                   : (f32x4){0.f, 0.f, 0.f, 0.f};

    // --- 3 interaction residuals ---
    for (int k = 0; k < NRI; ++k) {
        write_act_T(actA, w, lrow, kgrp, m);
        __syncthreads();
        stage_w(wch + (size_t)(2 * k) * 16384, wlds, t);
        __syncthreads();
        gemm_tile_T(actA, wlds, w, lrow, kgrp, bri1 + k * FDIM, acc);
        #pragma unroll
        for (int nf = 0; nf < 8; ++nf) h[nf] = acc[nf];
        write_act_T(actA, w, lrow, kgrp, h);
        __syncthreads();
        stage_w(wch + (size_t)(2 * k + 1) * 16384, wlds, t);
        __syncthreads();
        gemm_tile_T(actA, wlds, w, lrow, kgrp, bri2 + k * FDIM, acc);
        #pragma unroll
        for (int nf = 0; nf < 8; ++nf) m[nf] += acc[nf];
    }

    // --- outmix: m = u*feat + ssp(m)@Wd.T + bd ---
    write_act_T(actA, w, lrow, kgrp, m);
    __syncthreads();
    stage_w(wch + (size_t)6 * 16384, wlds, t);
    __syncthreads();
    gemm_tile_T(actA, wlds, w, lrow, kgrp, bd, acc);
    #pragma unroll
    for (int nf = 0; nf < 8; ++nf) {
        f32x4 fv = ok ? *(const f32x4*)(feat + (size_t)atom * FDIM + 16 * nf + 4 * kgrp)
                      : (f32x4){0.f, 0.f, 0.f, 0.f};
        f32x4 uv = *(const f32x4*)(u + 16 * nf + 4 * kgrp);
        m[nf] = uv * fv + acc[nf];
    }

    // --- 2 atomic residuals ---
    for (int k = 0; k < NRA; ++k) {
        write_act_T(actA, w, lrow, kgrp, m);
        __syncthreads();
        stage_w(wch + (size_t)(7 + 2 * k) * 16384, wlds, t);
        __syncthreads();
        gemm_tile_T(actA, wlds, w, lrow, kgrp, bra1 + k * FDIM, acc);
        #pragma unroll
        for (int nf = 0; nf < 8; ++nf) h[nf] = acc[nf];
        write_act_T(actA, w, lrow, kgrp, h);
        __syncthreads();
        stage_w(wch + (size_t)(8 + 2 * k) * 16384, wlds, t);
        __syncthreads();
        gemm_tile_T(actA, wlds, w, lrow, kgrp, bra2 + k * FDIM, acc);
        #pragma unroll
        for (int nf = 0; nf < 8; ++nf) m[nf] += acc[nf];
    }

    if (ok)
        #pragma unroll
        for (int nf = 0; nf < 8; ++nf)
            *(f32x4*)(xout + (size_t)atom * FDIM + 16 * nf + 4 * kgrp) = m[nf];
}

// ---------------------------------------------------------------------------
extern "C" void kernel_launch(void* const* d_in, const int* in_sizes, int n_in,
                              void* d_out, int out_size, void* d_ws, size_t ws_size,
                              hipStream_t stream)
{
    const float* feat  = (const float*)d_in[0];
    const float* desc  = (const float*)d_in[1];
    const int*   idx_i = (const int*)d_in[2];
    const int*   idx_j = (const int*)d_in[3];
    const float* Wdesc = (const float*)d_in[4];
    const float* Wi    = (const float*)d_in[5];
    const float* bi    = (const float*)d_in[6];
    const float* Wj    = (const float*)d_in[7];
    const float* bj    = (const float*)d_in[8];
    const float* Wri1  = (const float*)d_in[9];
    const float* bri1  = (const float*)d_in[10];
    const float* Wri2  = (const float*)d_in[11];
    const float* bri2  = (const float*)d_in[12];
    const float* Wd    = (const float*)d_in[13];
    const float* bd    = (const float*)d_in[14];
    const float* u     = (const float*)d_in[15];
    const float* Wra1  = (const float*)d_in[16];
    const float* bra1  = (const float*)d_in[17];
    const float* Wra2  = (const float*)d_in[18];
    const float* bra2  = (const float*)d_in[19];

    char* wsp = (char*)d_ws;
    float* msg = (float*)wsp;                             // NA*F f32
    size_t off = (size_t)NA * FDIM * sizeof(float);
    ushort_t* xja = (ushort_t*)(wsp + off);               // NA*F bf16
    off += (size_t)NA * FDIM * sizeof(ushort_t);
    ushort_t* wbf = (ushort_t*)(wsp + off);               // bf16 weights
    off += (((size_t)221184 * sizeof(ushort_t)) + 255) & ~(size_t)255;

    float* xout = (float*)d_out;
    const int nblk64 = (NA + 63) / 64;

    k_wconv<<<dim3(24, 8), 256, 0, stream>>>(Wdesc, Wi, Wj, Wri1, Wri2, Wd, Wra1, Wra2, wbf);
    k_node_pre<<<nblk64, 256, 0, stream>>>(feat, wbf, bi, bj, msg, xja);
    k_edge_fused<<<NE / 64, 256, 0, stream>>>(desc, wbf, idx_i, idx_j, xja, msg);
    k_chain<<<nblk64, 256, 0, stream>>>(msg, feat, u, wbf + 40960,
                                        bri1, bri2, bd, bra1, bra2, xout);
}

// Round 11
// 286.743 us; speedup vs baseline: 1.0423x; 1.0423x over previous
//
#include <hip/hip_runtime.h>
#include <math.h>

#define NA 50000
#define NE 800000
#define FDIM 128
#define KDIM 64
#define NRI 3
#define NRA 2

typedef unsigned short ushort_t;
typedef unsigned int uint_t;
typedef __attribute__((ext_vector_type(8))) short short8v;
typedef __attribute__((ext_vector_type(4))) float f32x4;
typedef __attribute__((ext_vector_type(4))) unsigned short u16x4;

// ssp(x) = softplus(x) - ln2 via hardware v_exp_f32/v_log_f32.
__device__ __forceinline__ float ssp_f(float x) {
    float e = __expf(-fabsf(x));
    return fmaxf(x, 0.0f) + __logf(1.0f + e) - 0.69314718055994530942f;
}
__device__ __forceinline__ ushort_t f2bf(float x) {
    unsigned u = __float_as_uint(x);
    u += 0x7FFFu + ((u >> 16) & 1u);          // RNE
    return (ushort_t)(u >> 16);
}
__device__ __forceinline__ float bf2f(ushort_t h) {
    return __uint_as_float(((unsigned)h) << 16);
}
__device__ __forceinline__ f32x4 ssp4(f32x4 v) {
    f32x4 r;
    #pragma unroll
    for (int j = 0; j < 4; ++j) r[j] = ssp_f(v[j]);
    return r;
}
__device__ __forceinline__ u16x4 pack4(f32x4 v) {
    u16x4 p;
    #pragma unroll
    for (int j = 0; j < 4; ++j) p[j] = f2bf(v[j]);
    return p;
}

// ---------------------------------------------------------------------------
// Weight pre-convert (once): fp32 -> bf16 into ws.
// wbf layout (ushort offsets): Wdesc@0 (8192), Wi@8192, Wj@24576,
// chain@40960: [Wri1_0,Wri2_0,Wri1_1,Wri2_1,Wri1_2,Wri2_2,Wd,Wra1_0,Wra2_0,Wra1_1,Wra2_1]
// ---------------------------------------------------------------------------
__global__ __launch_bounds__(256) void k_wconv(
    const float* __restrict__ Wdesc, const float* __restrict__ Wi,
    const float* __restrict__ Wj,    const float* __restrict__ Wri1,
    const float* __restrict__ Wri2,  const float* __restrict__ Wd,
    const float* __restrict__ Wra1,  const float* __restrict__ Wra2,
    ushort_t* __restrict__ wbf)
{
    const int seg = blockIdx.y;
    const int idx = blockIdx.x * 2048 + threadIdx.x * 8;
    const float* s; ushort_t* d; int cnt;
    const int CH = 40960;
    switch (seg) {
    case 0: cnt = 8192;  if (idx >= cnt) return; s = Wdesc + idx; d = wbf + idx; break;
    case 1: cnt = 16384; if (idx >= cnt) return; s = Wi + idx;    d = wbf + 8192 + idx; break;
    case 2: cnt = 16384; if (idx >= cnt) return; s = Wj + idx;    d = wbf + 24576 + idx; break;
    case 3: { cnt = 3*16384; if (idx >= cnt) return; int k = idx/16384, o = idx - k*16384;
              s = Wri1 + idx; d = wbf + CH + (2*k)*16384 + o; break; }
    case 4: { cnt = 3*16384; if (idx >= cnt) return; int k = idx/16384, o = idx - k*16384;
              s = Wri2 + idx; d = wbf + CH + (2*k+1)*16384 + o; break; }
    case 5: cnt = 16384; if (idx >= cnt) return; s = Wd + idx; d = wbf + CH + 6*16384 + idx; break;
    case 6: { cnt = 2*16384; if (idx >= cnt) return; int k = idx/16384, o = idx - k*16384;
              s = Wra1 + idx; d = wbf + CH + (7+2*k)*16384 + o; break; }
    default:{ cnt = 2*16384; if (idx >= cnt) return; int k = idx/16384, o = idx - k*16384;
              s = Wra2 + idx; d = wbf + CH + (8+2*k)*16384 + o; break; }
    }
    #pragma unroll
    for (int j = 0; j < 8; ++j) d[j] = f2bf(s[j]);
}

// ---------------------------------------------------------------------------
// Transposed-GEMM helpers. Wave w owns atoms {16w + lrow}; each lane holds
// features {16nf + 4kgrp + r} of its atom. C[row=W-row(feature)][col=act-row(atom)].
// ---------------------------------------------------------------------------
__device__ __forceinline__ void stage_w(const ushort_t* __restrict__ src,
                                        ushort_t (*wlds)[136], int t)
{
    const int r = t >> 1, c0 = (t & 1) * 64;
    const short8v* s = (const short8v*)(src + (size_t)r * FDIM + c0);
    #pragma unroll
    for (int q = 0; q < 8; ++q)
        *(short8v*)&wlds[r][c0 + q * 8] = s[q];
}

__device__ __forceinline__ void gemm_tile_T(
    const ushort_t (*actA)[136], const ushort_t (*wlds)[136],
    int w, int lrow, int kgrp, const float* __restrict__ bias, f32x4 acc[8])
{
    short8v bfr[4];
    #pragma unroll
    for (int ks = 0; ks < 4; ++ks)
        bfr[ks] = *(const short8v*)&actA[16 * w + lrow][ks * 32 + kgrp * 8];
    #pragma unroll
    for (int nf = 0; nf < 8; ++nf)
        acc[nf] = *(const f32x4*)(bias + 16 * nf + 4 * kgrp);
    #pragma unroll
    for (int nf = 0; nf < 8; ++nf)
        #pragma unroll
        for (int ks = 0; ks < 4; ++ks) {
            short8v av = *(const short8v*)&wlds[16 * nf + lrow][ks * 32 + kgrp * 8];
            acc[nf] = __builtin_amdgcn_mfma_f32_16x16x32_bf16(av, bfr[ks], acc[nf], 0, 0, 0);
        }
}

// act = ssp(v), packed b64 writes into this wave's own 16 rows
__device__ __forceinline__ void write_act_T(
    ushort_t (*actA)[136], int w, int lrow, int kgrp, const f32x4 v[8])
{
    #pragma unroll
    for (int nf = 0; nf < 8; ++nf)
        *(u16x4*)&actA[16 * w + lrow][16 * nf + 4 * kgrp] = pack4(ssp4(v[nf]));
}

// ---------------------------------------------------------------------------
// Node pre (MFMA, transposed): xi = ssp(ssp(feat)@Wi.T+bi) -> msg (f32)
//                              xja = ssp(ssp(feat)@Wj.T+bj) -> bf16
// ---------------------------------------------------------------------------
__global__ __launch_bounds__(256) void k_node_pre(
    const float* __restrict__ feat, const ushort_t* __restrict__ wbf,
    const float* __restrict__ bi, const float* __restrict__ bj,
    float* __restrict__ xi_out, ushort_t* __restrict__ xja_out)
{
    __shared__ ushort_t actA[64][136];
    __shared__ ushort_t wlds[128][136];
    const int t = threadIdx.x, lane = t & 63, w = t >> 6;
    const int lrow = lane & 15, kgrp = lane >> 4;
    const int atom = blockIdx.x * 64 + 16 * w + lrow;
    const bool ok = atom < NA;

    f32x4 v[8];
    #pragma unroll
    for (int nf = 0; nf < 8; ++nf)
        v[nf] = ok ? *(const f32x4*)(feat + (size_t)atom * FDIM + 16 * nf + 4 * kgrp)
                   : (f32x4){0.f, 0.f, 0.f, 0.f};
    write_act_T(actA, w, lrow, kgrp, v);
    __syncthreads();
    stage_w(wbf + 8192, wlds, t);
    __syncthreads();
    f32x4 acc[8];
    gemm_tile_T(actA, wlds, w, lrow, kgrp, bi, acc);
    if (ok)
        #pragma unroll
        for (int nf = 0; nf < 8; ++nf)
            *(f32x4*)(xi_out + (size_t)atom * FDIM + 16 * nf + 4 * kgrp) = ssp4(acc[nf]);
    __syncthreads();
    stage_w(wbf + 24576, wlds, t);
    __syncthreads();
    gemm_tile_T(actA, wlds, w, lrow, kgrp, bj, acc);
    if (ok)
        #pragma unroll
        for (int nf = 0; nf < 8; ++nf)
            *(u16x4*)(xja_out + (size_t)atom * FDIM + 16 * nf + 4 * kgrp) = pack4(ssp4(acc[nf]));
}

// ---------------------------------------------------------------------------
// Fused edge kernel: per block of 64 contiguous edges,
//   p[e][f] = (desc[e]@Wdesc[f]) * xja[idx_j[e]][f]   (MFMA, bf16 in LDS)
// then feature-parallel segmented sum over the 64 rows (idx_i sorted ->
// contiguous runs), flushed with native f32 atomics into msg.
// bf16 p-tile = 17.7 KB LDS -> 8 blocks/CU possible; NO min-wave bound so the
// compiler keeps ~64 VGPR without spilling (round-10 spills cost 77 MB).
// ---------------------------------------------------------------------------
__device__ __forceinline__ short8v pack8(const float* p) {
    short8v r;
    #pragma unroll
    for (int j = 0; j < 8; ++j) r[j] = (short)f2bf(p[j]);
    return r;
}

__global__ __launch_bounds__(256) void k_edge_fused(
    const float* __restrict__ desc, const ushort_t* __restrict__ wdbf,
    const int* __restrict__ idx_i, const int* __restrict__ idx_j,
    const ushort_t* __restrict__ xja,
    float* __restrict__ msg)
{
    __shared__ ushort_t pl[64][136];   // bf16 p tile (17.4 KB)
    __shared__ int ii[64];
    const int t = threadIdx.x, lane = t & 63, w = t >> 6;
    const int lrow = lane & 15, kgrp = lane >> 4;
    const int e0 = blockIdx.x * 64;
    const int er = e0 + w * 16 + lrow;          // this lane's edge (64 | NE)

    // longest chains first: idx_j (heads gather chain), then desc (HBM)
    const int jj = idx_j[er];
    const float* q = desc + (size_t)er * KDIM + kgrp * 8;
    float t0[8], t1[8];
    *(float4*)(t0)     = *(const float4*)q;
    *(float4*)(t0 + 4) = *(const float4*)(q + 4);
    *(float4*)(t1)     = *(const float4*)(q + 32);
    *(float4*)(t1 + 4) = *(const float4*)(q + 36);

    if (t < 64) ii[t] = idx_i[e0 + t];

    // Wdesc A-fragments (bf16, L2-hot)
    short8v a[8][2];
    #pragma unroll
    for (int nf = 0; nf < 8; ++nf)
        #pragma unroll
        for (int ks = 0; ks < 2; ++ks)
            a[nf][ks] = *(const short8v*)(wdbf + (size_t)(16 * nf + lrow) * KDIM
                                          + ks * 32 + kgrp * 8);

    short8v b0 = pack8(t0), b1 = pack8(t1);

    f32x4 acc[8];
    #pragma unroll
    for (int nf = 0; nf < 8; ++nf) acc[nf] = (f32x4){0.f, 0.f, 0.f, 0.f};
    #pragma unroll
    for (int nf = 0; nf < 8; ++nf) {
        acc[nf] = __builtin_amdgcn_mfma_f32_16x16x32_bf16(a[nf][0], b0, acc[nf], 0,0,0);
        acc[nf] = __builtin_amdgcn_mfma_f32_16x16x32_bf16(a[nf][1], b1, acc[nf], 0,0,0);
    }

    // gather-multiply, park in LDS as bf16
    #pragma unroll
    for (int nf = 0; nf < 8; ++nf) {
        u16x4 xv = *(const u16x4*)(xja + (size_t)jj * FDIM + 16 * nf + 4 * kgrp);
        f32x4 pr;
        #pragma unroll
        for (int j = 0; j < 4; ++j) pr[j] = acc[nf][j] * bf2f(xv[j]);
        *(u16x4*)&pl[w * 16 + lrow][16 * nf + 4 * kgrp] = pack4(pr);
    }
    __syncthreads();

    // segmented flush: thread = (feature, half); walk 32 rows in groups of 4
    // (prefetch LDS reads ahead of the divergent run-boundary branch).
    const int f = t & 127, h = t >> 7;
    const int r0 = h * 32;
    float s = 0.0f;
    int cur = ii[r0];
    #pragma unroll
    for (int g = 0; g < 8; ++g) {
        float v[4];
        int id[4];
        #pragma unroll
        for (int qq = 0; qq < 4; ++qq) {
            v[qq]  = bf2f(pl[r0 + g * 4 + qq][f]);
            id[qq] = ii[r0 + g * 4 + qq];
        }
        #pragma unroll
        for (int qq = 0; qq < 4; ++qq) {
            if (id[qq] != cur) {
                unsafeAtomicAdd(&msg[(size_t)cur * FDIM + f], s);
                s = 0.0f; cur = id[qq];
            }
            s += v[qq];
        }
    }
    unsafeAtomicAdd(&msg[(size_t)cur * FDIM + f], s);
}

// ---------------------------------------------------------------------------
// Fused node chain (transposed): 3 residuals + outmix + 2 residuals.
// m carried as f32x4[8] per thread (atom fixed per lane, features packed).
// ---------------------------------------------------------------------------
__global__ __launch_bounds__(256) void k_chain(
    const float* __restrict__ msgp, const float* __restrict__ feat,
    const float* __restrict__ u, const ushort_t* __restrict__ wch,
    const float* __restrict__ bri1, const float* __restrict__ bri2,
    const float* __restrict__ bd,
    const float* __restrict__ bra1, const float* __restrict__ bra2,
    float* __restrict__ xout)
{
    __shared__ ushort_t actA[64][136];
    __shared__ ushort_t wlds[128][136];
    const int t = threadIdx.x, lane = t & 63, w = t >> 6;
    const int lrow = lane & 15, kgrp = lane >> 4;
    const int atom = blockIdx.x * 64 + 16 * w + lrow;
    const bool ok = atom < NA;

    f32x4 m[8], h[8], acc[8];
    #pragma unroll
    for (int nf = 0; nf < 8; ++nf)
        m[nf] = ok ? *(const f32x4*)(msgp + (size_t)atom * FDIM + 16 * nf + 4 * kgrp)
                   : (f32x4){0.f, 0.f, 0.f, 0.f};

    // --- 3 interaction residuals ---
    for (int k = 0; k < NRI; ++k) {
        write_act_T(actA, w, lrow, kgrp, m);
        __syncthreads();
        stage_w(wch + (size_t)(2 * k) * 16384, wlds, t);
        __syncthreads();
        gemm_tile_T(actA, wlds, w, lrow, kgrp, bri1 + k * FDIM, acc);
        #pragma unroll
        for (int nf = 0; nf < 8; ++nf) h[nf] = acc[nf];
        write_act_T(actA, w, lrow, kgrp, h);
        __syncthreads();
        stage_w(wch + (size_t)(2 * k + 1) * 16384, wlds, t);
        __syncthreads();
        gemm_tile_T(actA, wlds, w, lrow, kgrp, bri2 + k * FDIM, acc);
        #pragma unroll
        for (int nf = 0; nf < 8; ++nf) m[nf] += acc[nf];
    }

    // --- outmix: m = u*feat + ssp(m)@Wd.T + bd ---
    write_act_T(actA, w, lrow, kgrp, m);
    __syncthreads();
    stage_w(wch + (size_t)6 * 16384, wlds, t);
    __syncthreads();
    gemm_tile_T(actA, wlds, w, lrow, kgrp, bd, acc);
    #pragma unroll
    for (int nf = 0; nf < 8; ++nf) {
        f32x4 fv = ok ? *(const f32x4*)(feat + (size_t)atom * FDIM + 16 * nf + 4 * kgrp)
                      : (f32x4){0.f, 0.f, 0.f, 0.f};
        f32x4 uv = *(const f32x4*)(u + 16 * nf + 4 * kgrp);
        m[nf] = uv * fv + acc[nf];
    }

    // --- 2 atomic residuals ---
    for (int k = 0; k < NRA; ++k) {
        write_act_T(actA, w, lrow, kgrp, m);
        __syncthreads();
        stage_w(wch + (size_t)(7 + 2 * k) * 16384, wlds, t);
        __syncthreads();
        gemm_tile_T(actA, wlds, w, lrow, kgrp, bra1 + k * FDIM, acc);
        #pragma unroll
        for (int nf = 0; nf < 8; ++nf) h[nf] = acc[nf];
        write_act_T(actA, w, lrow, kgrp, h);
        __syncthreads();
        stage_w(wch + (size_t)(8 + 2 * k) * 16384, wlds, t);
        __syncthreads();
        gemm_tile_T(actA, wlds, w, lrow, kgrp, bra2 + k * FDIM, acc);
        #pragma unroll
        for (int nf = 0; nf < 8; ++nf) m[nf] += acc[nf];
    }

    if (ok)
        #pragma unroll
        for (int nf = 0; nf < 8; ++nf)
            *(f32x4*)(xout + (size_t)atom * FDIM + 16 * nf + 4 * kgrp) = m[nf];
}

// ---------------------------------------------------------------------------
extern "C" void kernel_launch(void* const* d_in, const int* in_sizes, int n_in,
                              void* d_out, int out_size, void* d_ws, size_t ws_size,
                              hipStream_t stream)
{
    const float* feat  = (const float*)d_in[0];
    const float* desc  = (const float*)d_in[1];
    const int*   idx_i = (const int*)d_in[2];
    const int*   idx_j = (const int*)d_in[3];
    const float* Wdesc = (const float*)d_in[4];
    const float* Wi    = (const float*)d_in[5];
    const float* bi    = (const float*)d_in[6];
    const float* Wj    = (const float*)d_in[7];
    const float* bj    = (const float*)d_in[8];
    const float* Wri1  = (const float*)d_in[9];
    const float* bri1  = (const float*)d_in[10];
    const float* Wri2  = (const float*)d_in[11];
    const float* bri2  = (const float*)d_in[12];
    const float* Wd    = (const float*)d_in[13];
    const float* bd    = (const float*)d_in[14];
    const float* u     = (const float*)d_in[15];
    const float* Wra1  = (const float*)d_in[16];
    const float* bra1  = (const float*)d_in[17];
    const float* Wra2  = (const float*)d_in[18];
    const float* bra2  = (const float*)d_in[19];

    char* wsp = (char*)d_ws;
    float* msg = (float*)wsp;                             // NA*F f32
    size_t off = (size_t)NA * FDIM * sizeof(float);
    ushort_t* xja = (ushort_t*)(wsp + off);               // NA*F bf16
    off += (size_t)NA * FDIM * sizeof(ushort_t);
    ushort_t* wbf = (ushort_t*)(wsp + off);               // bf16 weights
    off += (((size_t)221184 * sizeof(ushort_t)) + 255) & ~(size_t)255;

    float* xout = (float*)d_out;
    const int nblk64 = (NA + 63) / 64;

    k_wconv<<<dim3(24, 8), 256, 0, stream>>>(Wdesc, Wi, Wj, Wri1, Wri2, Wd, Wra1, Wra2, wbf);
    k_node_pre<<<nblk64, 256, 0, stream>>>(feat, wbf, bi, bj, msg, xja);
    k_edge_fused<<<NE / 64, 256, 0, stream>>>(desc, wbf, idx_i, idx_j, xja, msg);
    k_chain<<<nblk64, 256, 0, stream>>>(msg, feat, u, wbf + 40960,
                                        bri1, bri2, bd, bra1, bra2, xout);
}

// Round 12
// 231.536 us; speedup vs baseline: 1.2908x; 1.2384x over previous
//
#include <hip/hip_runtime.h>
#include <math.h>

#define NA 50000
#define NE 800000
#define FDIM 128
#define KDIM 64
#define NRI 3
#define NRA 2
#define ETILES 10   // 64-edge tiles per block; NE / (64*ETILES) = 1250 exact

typedef unsigned short ushort_t;
typedef unsigned int uint_t;
typedef __attribute__((ext_vector_type(8))) short short8v;
typedef __attribute__((ext_vector_type(4))) float f32x4;
typedef __attribute__((ext_vector_type(4))) unsigned short u16x4;

// ssp(x) = softplus(x) - ln2 via hardware v_exp_f32/v_log_f32.
__device__ __forceinline__ float ssp_f(float x) {
    float e = __expf(-fabsf(x));
    return fmaxf(x, 0.0f) + __logf(1.0f + e) - 0.69314718055994530942f;
}
__device__ __forceinline__ ushort_t f2bf(float x) {
    unsigned u = __float_as_uint(x);
    u += 0x7FFFu + ((u >> 16) & 1u);          // RNE
    return (ushort_t)(u >> 16);
}
__device__ __forceinline__ float bf2f(ushort_t h) {
    return __uint_as_float(((unsigned)h) << 16);
}
__device__ __forceinline__ f32x4 ssp4(f32x4 v) {
    f32x4 r;
    #pragma unroll
    for (int j = 0; j < 4; ++j) r[j] = ssp_f(v[j]);
    return r;
}
__device__ __forceinline__ u16x4 pack4(f32x4 v) {
    u16x4 p;
    #pragma unroll
    for (int j = 0; j < 4; ++j) p[j] = f2bf(v[j]);
    return p;
}

// ---------------------------------------------------------------------------
// Weight pre-convert (once): fp32 -> bf16 into ws.
// wbf layout (ushort offsets): Wdesc@0 (8192), Wi@8192, Wj@24576,
// chain@40960: [Wri1_0,Wri2_0,Wri1_1,Wri2_1,Wri1_2,Wri2_2,Wd,Wra1_0,Wra2_0,Wra1_1,Wra2_1]
// ---------------------------------------------------------------------------
__global__ __launch_bounds__(256) void k_wconv(
    const float* __restrict__ Wdesc, const float* __restrict__ Wi,
    const float* __restrict__ Wj,    const float* __restrict__ Wri1,
    const float* __restrict__ Wri2,  const float* __restrict__ Wd,
    const float* __restrict__ Wra1,  const float* __restrict__ Wra2,
    ushort_t* __restrict__ wbf)
{
    const int seg = blockIdx.y;
    const int idx = blockIdx.x * 2048 + threadIdx.x * 8;
    const float* s; ushort_t* d; int cnt;
    const int CH = 40960;
    switch (seg) {
    case 0: cnt = 8192;  if (idx >= cnt) return; s = Wdesc + idx; d = wbf + idx; break;
    case 1: cnt = 16384; if (idx >= cnt) return; s = Wi + idx;    d = wbf + 8192 + idx; break;
    case 2: cnt = 16384; if (idx >= cnt) return; s = Wj + idx;    d = wbf + 24576 + idx; break;
    case 3: { cnt = 3*16384; if (idx >= cnt) return; int k = idx/16384, o = idx - k*16384;
              s = Wri1 + idx; d = wbf + CH + (2*k)*16384 + o; break; }
    case 4: { cnt = 3*16384; if (idx >= cnt) return; int k = idx/16384, o = idx - k*16384;
              s = Wri2 + idx; d = wbf + CH + (2*k+1)*16384 + o; break; }
    case 5: cnt = 16384; if (idx >= cnt) return; s = Wd + idx; d = wbf + CH + 6*16384 + idx; break;
    case 6: { cnt = 2*16384; if (idx >= cnt) return; int k = idx/16384, o = idx - k*16384;
              s = Wra1 + idx; d = wbf + CH + (7+2*k)*16384 + o; break; }
    default:{ cnt = 2*16384; if (idx >= cnt) return; int k = idx/16384, o = idx - k*16384;
              s = Wra2 + idx; d = wbf + CH + (8+2*k)*16384 + o; break; }
    }
    #pragma unroll
    for (int j = 0; j < 8; ++j) d[j] = f2bf(s[j]);
}

// ---------------------------------------------------------------------------
// Transposed-GEMM helpers. Wave w owns atoms {16w + lrow}; each lane holds
// features {16nf + 4kgrp + r} of its atom. C[row=W-row(feature)][col=act-row(atom)].
// ---------------------------------------------------------------------------
__device__ __forceinline__ void stage_w(const ushort_t* __restrict__ src,
                                        ushort_t (*wlds)[136], int t)
{
    const int r = t >> 1, c0 = (t & 1) * 64;
    const short8v* s = (const short8v*)(src + (size_t)r * FDIM + c0);
    #pragma unroll
    for (int q = 0; q < 8; ++q)
        *(short8v*)&wlds[r][c0 + q * 8] = s[q];
}

__device__ __forceinline__ void gemm_tile_T(
    const ushort_t (*actA)[136], const ushort_t (*wlds)[136],
    int w, int lrow, int kgrp, const float* __restrict__ bias, f32x4 acc[8])
{
    short8v bfr[4];
    #pragma unroll
    for (int ks = 0; ks < 4; ++ks)
        bfr[ks] = *(const short8v*)&actA[16 * w + lrow][ks * 32 + kgrp * 8];
    #pragma unroll
    for (int nf = 0; nf < 8; ++nf)
        acc[nf] = *(const f32x4*)(bias + 16 * nf + 4 * kgrp);
    #pragma unroll
    for (int nf = 0; nf < 8; ++nf)
        #pragma unroll
        for (int ks = 0; ks < 4; ++ks) {
            short8v av = *(const short8v*)&wlds[16 * nf + lrow][ks * 32 + kgrp * 8];
            acc[nf] = __builtin_amdgcn_mfma_f32_16x16x32_bf16(av, bfr[ks], acc[nf], 0, 0, 0);
        }
}

// act = ssp(v), packed b64 writes into this wave's own 16 rows
__device__ __forceinline__ void write_act_T(
    ushort_t (*actA)[136], int w, int lrow, int kgrp, const f32x4 v[8])
{
    #pragma unroll
    for (int nf = 0; nf < 8; ++nf)
        *(u16x4*)&actA[16 * w + lrow][16 * nf + 4 * kgrp] = pack4(ssp4(v[nf]));
}

// ---------------------------------------------------------------------------
// Node pre (MFMA, transposed): xi = ssp(ssp(feat)@Wi.T+bi) -> msg (f32)
//                              xja = ssp(ssp(feat)@Wj.T+bj) -> bf16
// ---------------------------------------------------------------------------
__global__ __launch_bounds__(256) void k_node_pre(
    const float* __restrict__ feat, const ushort_t* __restrict__ wbf,
    const float* __restrict__ bi, const float* __restrict__ bj,
    float* __restrict__ xi_out, ushort_t* __restrict__ xja_out)
{
    __shared__ ushort_t actA[64][136];
    __shared__ ushort_t wlds[128][136];
    const int t = threadIdx.x, lane = t & 63, w = t >> 6;
    const int lrow = lane & 15, kgrp = lane >> 4;
    const int atom = blockIdx.x * 64 + 16 * w + lrow;
    const bool ok = atom < NA;

    f32x4 v[8];
    #pragma unroll
    for (int nf = 0; nf < 8; ++nf)
        v[nf] = ok ? *(const f32x4*)(feat + (size_t)atom * FDIM + 16 * nf + 4 * kgrp)
                   : (f32x4){0.f, 0.f, 0.f, 0.f};
    write_act_T(actA, w, lrow, kgrp, v);
    __syncthreads();
    stage_w(wbf + 8192, wlds, t);
    __syncthreads();
    f32x4 acc[8];
    gemm_tile_T(actA, wlds, w, lrow, kgrp, bi, acc);
    if (ok)
        #pragma unroll
        for (int nf = 0; nf < 8; ++nf)
            *(f32x4*)(xi_out + (size_t)atom * FDIM + 16 * nf + 4 * kgrp) = ssp4(acc[nf]);
    __syncthreads();
    stage_w(wbf + 24576, wlds, t);
    __syncthreads();
    gemm_tile_T(actA, wlds, w, lrow, kgrp, bj, acc);
    if (ok)
        #pragma unroll
        for (int nf = 0; nf < 8; ++nf)
            *(u16x4*)(xja_out + (size_t)atom * FDIM + 16 * nf + 4 * kgrp) = pack4(ssp4(acc[nf]));
}

// ---------------------------------------------------------------------------
// Fused edge kernel, ETILES tiles of 64 edges per block:
//   p[e][f] = (desc[e]@Wdesc[f]) * xja[idx_j[e]][f]   (MFMA, bf16 in LDS)
// then feature-parallel segmented sum per tile, atomically flushed to msg.
// Wdesc fragments loaded ONCE per block (was once per 64 edges = 800 MB L2);
// next tile's desc/idx loads issue before the barrier -> overlap the flush.
// ---------------------------------------------------------------------------
__device__ __forceinline__ short8v pack8(const float* p) {
    short8v r;
    #pragma unroll
    for (int j = 0; j < 8; ++j) r[j] = (short)f2bf(p[j]);
    return r;
}

__global__ __launch_bounds__(256) void k_edge_fused(
    const float* __restrict__ desc, const ushort_t* __restrict__ wdbf,
    const int* __restrict__ idx_i, const int* __restrict__ idx_j,
    const ushort_t* __restrict__ xja,
    float* __restrict__ msg)
{
    __shared__ ushort_t pl[64][136];   // bf16 p tile (17.4 KB)
    __shared__ int ii[64];
    const int t = threadIdx.x, lane = t & 63, w = t >> 6;
    const int lrow = lane & 15, kgrp = lane >> 4;
    const int ebase = blockIdx.x * (64 * ETILES);
    const int eoff = w * 16 + lrow;

    // Wdesc A-fragments: once per block
    short8v a[8][2];
    #pragma unroll
    for (int nf = 0; nf < 8; ++nf)
        #pragma unroll
        for (int ks = 0; ks < 2; ++ks)
            a[nf][ks] = *(const short8v*)(wdbf + (size_t)(16 * nf + lrow) * KDIM
                                          + ks * 32 + kgrp * 8);

    // prefetch tile 0
    int er = ebase + eoff;
    int jj = idx_j[er];
    float t0[8], t1[8];
    {
        const float* q = desc + (size_t)er * KDIM + kgrp * 8;
        *(float4*)(t0)     = *(const float4*)q;
        *(float4*)(t0 + 4) = *(const float4*)(q + 4);
        *(float4*)(t1)     = *(const float4*)(q + 32);
        *(float4*)(t1 + 4) = *(const float4*)(q + 36);
    }

    for (int tt = 0; tt < ETILES; ++tt) {
        if (t < 64) ii[t] = idx_i[ebase + tt * 64 + t];

        short8v b0 = pack8(t0), b1 = pack8(t1);
        f32x4 acc[8];
        #pragma unroll
        for (int nf = 0; nf < 8; ++nf) acc[nf] = (f32x4){0.f, 0.f, 0.f, 0.f};
        #pragma unroll
        for (int nf = 0; nf < 8; ++nf) {
            acc[nf] = __builtin_amdgcn_mfma_f32_16x16x32_bf16(a[nf][0], b0, acc[nf], 0,0,0);
            acc[nf] = __builtin_amdgcn_mfma_f32_16x16x32_bf16(a[nf][1], b1, acc[nf], 0,0,0);
        }

        // gather-multiply, park in LDS as bf16
        #pragma unroll
        for (int nf = 0; nf < 8; ++nf) {
            u16x4 xv = *(const u16x4*)(xja + (size_t)jj * FDIM + 16 * nf + 4 * kgrp);
            f32x4 pr;
            #pragma unroll
            for (int j = 0; j < 4; ++j) pr[j] = acc[nf][j] * bf2f(xv[j]);
            *(u16x4*)&pl[w * 16 + lrow][16 * nf + 4 * kgrp] = pack4(pr);
        }

        // prefetch next tile (reuses t0/t1/jj registers; overlaps the flush)
        if (tt + 1 < ETILES) {
            er += 64;
            jj = idx_j[er];
            const float* q = desc + (size_t)er * KDIM + kgrp * 8;
            *(float4*)(t0)     = *(const float4*)q;
            *(float4*)(t0 + 4) = *(const float4*)(q + 4);
            *(float4*)(t1)     = *(const float4*)(q + 32);
            *(float4*)(t1 + 4) = *(const float4*)(q + 36);
        }

        __syncthreads();

        // segmented flush: thread = (feature, half); walk 32 rows in groups
        // of 4 (prefetch LDS reads ahead of the divergent boundary branch).
        const int f = t & 127, h = t >> 7;
        const int r0 = h * 32;
        float s = 0.0f;
        int cur = ii[r0];
        #pragma unroll
        for (int g = 0; g < 8; ++g) {
            float v[4];
            int id[4];
            #pragma unroll
            for (int qq = 0; qq < 4; ++qq) {
                v[qq]  = bf2f(pl[r0 + g * 4 + qq][f]);
                id[qq] = ii[r0 + g * 4 + qq];
            }
            #pragma unroll
            for (int qq = 0; qq < 4; ++qq) {
                if (id[qq] != cur) {
                    unsafeAtomicAdd(&msg[(size_t)cur * FDIM + f], s);
                    s = 0.0f; cur = id[qq];
                }
                s += v[qq];
            }
        }
        unsafeAtomicAdd(&msg[(size_t)cur * FDIM + f], s);

        __syncthreads();   // pl/ii reuse next iteration
    }
}

// ---------------------------------------------------------------------------
// Fused node chain (transposed): 3 residuals + outmix + 2 residuals.
// m carried as f32x4[8] per thread (atom fixed per lane, features packed).
// ---------------------------------------------------------------------------
__global__ __launch_bounds__(256) void k_chain(
    const float* __restrict__ msgp, const float* __restrict__ feat,
    const float* __restrict__ u, const ushort_t* __restrict__ wch,
    const float* __restrict__ bri1, const float* __restrict__ bri2,
    const float* __restrict__ bd,
    const float* __restrict__ bra1, const float* __restrict__ bra2,
    float* __restrict__ xout)
{
    __shared__ ushort_t actA[64][136];
    __shared__ ushort_t wlds[128][136];
    const int t = threadIdx.x, lane = t & 63, w = t >> 6;
    const int lrow = lane & 15, kgrp = lane >> 4;
    const int atom = blockIdx.x * 64 + 16 * w + lrow;
    const bool ok = atom < NA;

    f32x4 m[8], h[8], acc[8];
    #pragma unroll
    for (int nf = 0; nf < 8; ++nf)
        m[nf] = ok ? *(const f32x4*)(msgp + (size_t)atom * FDIM + 16 * nf + 4 * kgrp)
                   : (f32x4){0.f, 0.f, 0.f, 0.f};

    // --- 3 interaction residuals ---
    for (int k = 0; k < NRI; ++k) {
        write_act_T(actA, w, lrow, kgrp, m);
        __syncthreads();
        stage_w(wch + (size_t)(2 * k) * 16384, wlds, t);
        __syncthreads();
        gemm_tile_T(actA, wlds, w, lrow, kgrp, bri1 + k * FDIM, acc);
        #pragma unroll
        for (int nf = 0; nf < 8; ++nf) h[nf] = acc[nf];
        write_act_T(actA, w, lrow, kgrp, h);
        __syncthreads();
        stage_w(wch + (size_t)(2 * k + 1) * 16384, wlds, t);
        __syncthreads();
        gemm_tile_T(actA, wlds, w, lrow, kgrp, bri2 + k * FDIM, acc);
        #pragma unroll
        for (int nf = 0; nf < 8; ++nf) m[nf] += acc[nf];
    }

    // --- outmix: m = u*feat + ssp(m)@Wd.T + bd ---
    write_act_T(actA, w, lrow, kgrp, m);
    __syncthreads();
    stage_w(wch + (size_t)6 * 16384, wlds, t);
    __syncthreads();
    gemm_tile_T(actA, wlds, w, lrow, kgrp, bd, acc);
    #pragma unroll
    for (int nf = 0; nf < 8; ++nf) {
        f32x4 fv = ok ? *(const f32x4*)(feat + (size_t)atom * FDIM + 16 * nf + 4 * kgrp)
                      : (f32x4){0.f, 0.f, 0.f, 0.f};
        f32x4 uv = *(const f32x4*)(u + 16 * nf + 4 * kgrp);
        m[nf] = uv * fv + acc[nf];
    }

    // --- 2 atomic residuals ---
    for (int k = 0; k < NRA; ++k) {
        write_act_T(actA, w, lrow, kgrp, m);
        __syncthreads();
        stage_w(wch + (size_t)(7 + 2 * k) * 16384, wlds, t);
        __syncthreads();
        gemm_tile_T(actA, wlds, w, lrow, kgrp, bra1 + k * FDIM, acc);
        #pragma unroll
        for (int nf = 0; nf < 8; ++nf) h[nf] = acc[nf];
        write_act_T(actA, w, lrow, kgrp, h);
        __syncthreads();
        stage_w(wch + (size_t)(8 + 2 * k) * 16384, wlds, t);
        __syncthreads();
        gemm_tile_T(actA, wlds, w, lrow, kgrp, bra2 + k * FDIM, acc);
        #pragma unroll
        for (int nf = 0; nf < 8; ++nf) m[nf] += acc[nf];
    }

    if (ok)
        #pragma unroll
        for (int nf = 0; nf < 8; ++nf)
            *(f32x4*)(xout + (size_t)atom * FDIM + 16 * nf + 4 * kgrp) = m[nf];
}

// ---------------------------------------------------------------------------
extern "C" void kernel_launch(void* const* d_in, const int* in_sizes, int n_in,
                              void* d_out, int out_size, void* d_ws, size_t ws_size,
                              hipStream_t stream)
{
    const float* feat  = (const float*)d_in[0];
    const float* desc  = (const float*)d_in[1];
    const int*   idx_i = (const int*)d_in[2];
    const int*   idx_j = (const int*)d_in[3];
    const float* Wdesc = (const float*)d_in[4];
    const float* Wi    = (const float*)d_in[5];
    const float* bi    = (const float*)d_in[6];
    const float* Wj    = (const float*)d_in[7];
    const float* bj    = (const float*)d_in[8];
    const float* Wri1  = (const float*)d_in[9];
    const float* bri1  = (const float*)d_in[10];
    const float* Wri2  = (const float*)d_in[11];
    const float* bri2  = (const float*)d_in[12];
    const float* Wd    = (const float*)d_in[13];
    const float* bd    = (const float*)d_in[14];
    const float* u     = (const float*)d_in[15];
    const float* Wra1  = (const float*)d_in[16];
    const float* bra1  = (const float*)d_in[17];
    const float* Wra2  = (const float*)d_in[18];
    const float* bra2  = (const float*)d_in[19];

    char* wsp = (char*)d_ws;
    float* msg = (float*)wsp;                             // NA*F f32
    size_t off = (size_t)NA * FDIM * sizeof(float);
    ushort_t* xja = (ushort_t*)(wsp + off);               // NA*F bf16
    off += (size_t)NA * FDIM * sizeof(ushort_t);
    ushort_t* wbf = (ushort_t*)(wsp + off);               // bf16 weights
    off += (((size_t)221184 * sizeof(ushort_t)) + 255) & ~(size_t)255;

    float* xout = (float*)d_out;
    const int nblk64 = (NA + 63) / 64;

    k_wconv<<<dim3(24, 8), 256, 0, stream>>>(Wdesc, Wi, Wj, Wri1, Wri2, Wd, Wra1, Wra2, wbf);
    k_node_pre<<<nblk64, 256, 0, stream>>>(feat, wbf, bi, bj, msg, xja);
    k_edge_fused<<<NE / (64 * ETILES), 256, 0, stream>>>(desc, wbf, idx_i, idx_j, xja, msg);
    k_chain<<<nblk64, 256, 0, stream>>>(msg, feat, u, wbf + 40960,
                                        bri1, bri2, bd, bra1, bra2, xout);
}

// Round 13
// 226.125 us; speedup vs baseline: 1.3217x; 1.0239x over previous
//
#include <hip/hip_runtime.h>
#include <math.h>

#define NA 50000
#define NE 800000
#define FDIM 128
#define KDIM 64
#define NRI 3
#define NRA 2
#define ETILES 10   // 64-edge tiles per block; NE / (64*ETILES) = 1250 exact

typedef unsigned short ushort_t;
typedef unsigned int uint_t;
typedef __attribute__((ext_vector_type(8))) short short8v;
typedef __attribute__((ext_vector_type(4))) float f32x4;
typedef __attribute__((ext_vector_type(4))) unsigned short u16x4;

// ssp(x) = softplus(x) - ln2 via hardware v_exp_f32/v_log_f32.
__device__ __forceinline__ float ssp_f(float x) {
    float e = __expf(-fabsf(x));
    return fmaxf(x, 0.0f) + __logf(1.0f + e) - 0.69314718055994530942f;
}
__device__ __forceinline__ ushort_t f2bf(float x) {
    unsigned u = __float_as_uint(x);
    u += 0x7FFFu + ((u >> 16) & 1u);          // RNE
    return (ushort_t)(u >> 16);
}
__device__ __forceinline__ float bf2f(ushort_t h) {
    return __uint_as_float(((unsigned)h) << 16);
}
__device__ __forceinline__ f32x4 ssp4(f32x4 v) {
    f32x4 r;
    #pragma unroll
    for (int j = 0; j < 4; ++j) r[j] = ssp_f(v[j]);
    return r;
}
__device__ __forceinline__ u16x4 pack4(f32x4 v) {
    u16x4 p;
    #pragma unroll
    for (int j = 0; j < 4; ++j) p[j] = f2bf(v[j]);
    return p;
}

// ---------------------------------------------------------------------------
// Weight pre-convert (once): fp32 -> bf16 into ws.
// wbf layout (ushort offsets): Wdesc@0 (8192), Wi@8192, Wj@24576,
// chain@40960: [Wri1_0,Wri2_0,Wri1_1,Wri2_1,Wri1_2,Wri2_2,Wd,Wra1_0,Wra2_0,Wra1_1,Wra2_1]
// ---------------------------------------------------------------------------
__global__ __launch_bounds__(256) void k_wconv(
    const float* __restrict__ Wdesc, const float* __restrict__ Wi,
    const float* __restrict__ Wj,    const float* __restrict__ Wri1,
    const float* __restrict__ Wri2,  const float* __restrict__ Wd,
    const float* __restrict__ Wra1,  const float* __restrict__ Wra2,
    ushort_t* __restrict__ wbf)
{
    const int seg = blockIdx.y;
    const int idx = blockIdx.x * 2048 + threadIdx.x * 8;
    const float* s; ushort_t* d; int cnt;
    const int CH = 40960;
    switch (seg) {
    case 0: cnt = 8192;  if (idx >= cnt) return; s = Wdesc + idx; d = wbf + idx; break;
    case 1: cnt = 16384; if (idx >= cnt) return; s = Wi + idx;    d = wbf + 8192 + idx; break;
    case 2: cnt = 16384; if (idx >= cnt) return; s = Wj + idx;    d = wbf + 24576 + idx; break;
    case 3: { cnt = 3*16384; if (idx >= cnt) return; int k = idx/16384, o = idx - k*16384;
              s = Wri1 + idx; d = wbf + CH + (2*k)*16384 + o; break; }
    case 4: { cnt = 3*16384; if (idx >= cnt) return; int k = idx/16384, o = idx - k*16384;
              s = Wri2 + idx; d = wbf + CH + (2*k+1)*16384 + o; break; }
    case 5: cnt = 16384; if (idx >= cnt) return; s = Wd + idx; d = wbf + CH + 6*16384 + idx; break;
    case 6: { cnt = 2*16384; if (idx >= cnt) return; int k = idx/16384, o = idx - k*16384;
              s = Wra1 + idx; d = wbf + CH + (7+2*k)*16384 + o; break; }
    default:{ cnt = 2*16384; if (idx >= cnt) return; int k = idx/16384, o = idx - k*16384;
              s = Wra2 + idx; d = wbf + CH + (8+2*k)*16384 + o; break; }
    }
    #pragma unroll
    for (int j = 0; j < 8; ++j) d[j] = f2bf(s[j]);
}

// ---------------------------------------------------------------------------
// Transposed-GEMM helpers. Wave w owns atoms {16w + lrow}; each lane holds
// features {16nf + 4kgrp + r} of its atom. C[row=W-row(feature)][col=act-row(atom)].
// ---------------------------------------------------------------------------
__device__ __forceinline__ void stage_w(const ushort_t* __restrict__ src,
                                        ushort_t (*wlds)[136], int t)
{
    const int r = t >> 1, c0 = (t & 1) * 64;
    const short8v* s = (const short8v*)(src + (size_t)r * FDIM + c0);
    #pragma unroll
    for (int q = 0; q < 8; ++q)
        *(short8v*)&wlds[r][c0 + q * 8] = s[q];
}

__device__ __forceinline__ void gemm_tile_T(
    const ushort_t (*actA)[136], const ushort_t (*wlds)[136],
    int w, int lrow, int kgrp, const float* __restrict__ bias, f32x4 acc[8])
{
    short8v bfr[4];
    #pragma unroll
    for (int ks = 0; ks < 4; ++ks)
        bfr[ks] = *(const short8v*)&actA[16 * w + lrow][ks * 32 + kgrp * 8];
    #pragma unroll
    for (int nf = 0; nf < 8; ++nf)
        acc[nf] = *(const f32x4*)(bias + 16 * nf + 4 * kgrp);
    #pragma unroll
    for (int nf = 0; nf < 8; ++nf)
        #pragma unroll
        for (int ks = 0; ks < 4; ++ks) {
            short8v av = *(const short8v*)&wlds[16 * nf + lrow][ks * 32 + kgrp * 8];
            acc[nf] = __builtin_amdgcn_mfma_f32_16x16x32_bf16(av, bfr[ks], acc[nf], 0, 0, 0);
        }
}

// act = ssp(v), packed b64 writes into this wave's own 16 rows
__device__ __forceinline__ void write_act_T(
    ushort_t (*actA)[136], int w, int lrow, int kgrp, const f32x4 v[8])
{
    #pragma unroll
    for (int nf = 0; nf < 8; ++nf)
        *(u16x4*)&actA[16 * w + lrow][16 * nf + 4 * kgrp] = pack4(ssp4(v[nf]));
}

// ---------------------------------------------------------------------------
// Node pre (MFMA, transposed): xi = ssp(ssp(feat)@Wi.T+bi) -> msg (f32)
//                              xja = ssp(ssp(feat)@Wj.T+bj) -> bf16
// ---------------------------------------------------------------------------
__global__ __launch_bounds__(256) void k_node_pre(
    const float* __restrict__ feat, const ushort_t* __restrict__ wbf,
    const float* __restrict__ bi, const float* __restrict__ bj,
    float* __restrict__ xi_out, ushort_t* __restrict__ xja_out)
{
    __shared__ ushort_t actA[64][136];
    __shared__ ushort_t wlds[128][136];
    const int t = threadIdx.x, lane = t & 63, w = t >> 6;
    const int lrow = lane & 15, kgrp = lane >> 4;
    const int atom = blockIdx.x * 64 + 16 * w + lrow;
    const bool ok = atom < NA;

    f32x4 v[8];
    #pragma unroll
    for (int nf = 0; nf < 8; ++nf)
        v[nf] = ok ? *(const f32x4*)(feat + (size_t)atom * FDIM + 16 * nf + 4 * kgrp)
                   : (f32x4){0.f, 0.f, 0.f, 0.f};
    write_act_T(actA, w, lrow, kgrp, v);
    __syncthreads();
    stage_w(wbf + 8192, wlds, t);
    __syncthreads();
    f32x4 acc[8];
    gemm_tile_T(actA, wlds, w, lrow, kgrp, bi, acc);
    if (ok)
        #pragma unroll
        for (int nf = 0; nf < 8; ++nf)
            *(f32x4*)(xi_out + (size_t)atom * FDIM + 16 * nf + 4 * kgrp) = ssp4(acc[nf]);
    __syncthreads();
    stage_w(wbf + 24576, wlds, t);
    __syncthreads();
    gemm_tile_T(actA, wlds, w, lrow, kgrp, bj, acc);
    if (ok)
        #pragma unroll
        for (int nf = 0; nf < 8; ++nf)
            *(u16x4*)(xja_out + (size_t)atom * FDIM + 16 * nf + 4 * kgrp) = pack4(ssp4(acc[nf]));
}

// ---------------------------------------------------------------------------
// Fused edge kernel, ETILES tiles of 64 edges per block, software-pipelined:
//   p[e][f] = (desc[e]@Wdesc[f]) * xja[idx_j[e]][f]   (MFMA, bf16 in LDS)
// - pl/ii double-buffered -> ONE barrier per tile (flushers of buf A overlap
//   compute into buf B; reaching barrier t+1 implies flush of buf t-1 done)
// - desc AND xja-gather prefetched one tile ahead (gather off critical path)
// - segment carry (cur,s) held across tiles -> fewer atomics; each p still
//   added exactly once.
// ---------------------------------------------------------------------------
__device__ __forceinline__ short8v pack8(const float* p) {
    short8v r;
    #pragma unroll
    for (int j = 0; j < 8; ++j) r[j] = (short)f2bf(p[j]);
    return r;
}

__global__ __launch_bounds__(256) void k_edge_fused(
    const float* __restrict__ desc, const ushort_t* __restrict__ wdbf,
    const int* __restrict__ idx_i, const int* __restrict__ idx_j,
    const ushort_t* __restrict__ xja,
    float* __restrict__ msg)
{
    __shared__ ushort_t pl[2][64][136];   // 34.8 KB (double-buffered)
    __shared__ int ii[2][64];
    const int t = threadIdx.x, lane = t & 63, w = t >> 6;
    const int lrow = lane & 15, kgrp = lane >> 4;
    const int ebase = blockIdx.x * (64 * ETILES);
    const int eoff = w * 16 + lrow;

    // Wdesc A-fragments: once per block
    short8v a[8][2];
    #pragma unroll
    for (int nf = 0; nf < 8; ++nf)
        #pragma unroll
        for (int ks = 0; ks < 2; ++ks)
            a[nf][ks] = *(const short8v*)(wdbf + (size_t)(16 * nf + lrow) * KDIM
                                          + ks * 32 + kgrp * 8);

    // prefetch tile 0: desc, idx_j, and the xja gather
    int er = ebase + eoff;
    int jj = idx_j[er];
    float t0[8], t1[8];
    u16x4 xv[8];
    {
        const float* q = desc + (size_t)er * KDIM + kgrp * 8;
        *(float4*)(t0)     = *(const float4*)q;
        *(float4*)(t0 + 4) = *(const float4*)(q + 4);
        *(float4*)(t1)     = *(const float4*)(q + 32);
        *(float4*)(t1 + 4) = *(const float4*)(q + 36);
        #pragma unroll
        for (int nf = 0; nf < 8; ++nf)
            xv[nf] = *(const u16x4*)(xja + (size_t)jj * FDIM + 16 * nf + 4 * kgrp);
    }

    // carry state for the segmented flush (persists across tiles)
    const int f = t & 127, h = t >> 7;
    const int r0 = h * 32;
    float s = 0.0f;
    int cur = -1;

    for (int tt = 0; tt < ETILES; ++tt) {
        const int buf = tt & 1;
        if (t < 64) ii[buf][t] = idx_i[ebase + tt * 64 + t];

        short8v b0 = pack8(t0), b1 = pack8(t1);
        f32x4 acc[8];
        #pragma unroll
        for (int nf = 0; nf < 8; ++nf) acc[nf] = (f32x4){0.f, 0.f, 0.f, 0.f};
        #pragma unroll
        for (int nf = 0; nf < 8; ++nf) {
            acc[nf] = __builtin_amdgcn_mfma_f32_16x16x32_bf16(a[nf][0], b0, acc[nf], 0,0,0);
            acc[nf] = __builtin_amdgcn_mfma_f32_16x16x32_bf16(a[nf][1], b1, acc[nf], 0,0,0);
        }

        // multiply with prefetched gather, park in LDS as bf16
        #pragma unroll
        for (int nf = 0; nf < 8; ++nf) {
            f32x4 pr;
            #pragma unroll
            for (int j = 0; j < 4; ++j) pr[j] = acc[nf][j] * bf2f(xv[nf][j]);
            *(u16x4*)&pl[buf][w * 16 + lrow][16 * nf + 4 * kgrp] = pack4(pr);
        }

        // prefetch next tile (desc + jj + gather), overlaps barrier + flush
        if (tt + 1 < ETILES) {
            er += 64;
            jj = idx_j[er];
            const float* q = desc + (size_t)er * KDIM + kgrp * 8;
            *(float4*)(t0)     = *(const float4*)q;
            *(float4*)(t0 + 4) = *(const float4*)(q + 4);
            *(float4*)(t1)     = *(const float4*)(q + 32);
            *(float4*)(t1 + 4) = *(const float4*)(q + 36);
            #pragma unroll
            for (int nf = 0; nf < 8; ++nf)
                xv[nf] = *(const u16x4*)(xja + (size_t)jj * FDIM + 16 * nf + 4 * kgrp);
        }

        __syncthreads();   // pl[buf]/ii[buf] complete; buf^1 flush finished last iter

        // segmented flush of pl[buf] with cross-tile carry
        #pragma unroll
        for (int g = 0; g < 8; ++g) {
            float v[4];
            int id[4];
            #pragma unroll
            for (int qq = 0; qq < 4; ++qq) {
                v[qq]  = bf2f(pl[buf][r0 + g * 4 + qq][f]);
                id[qq] = ii[buf][r0 + g * 4 + qq];
            }
            #pragma unroll
            for (int qq = 0; qq < 4; ++qq) {
                if (id[qq] != cur) {
                    if (cur >= 0) unsafeAtomicAdd(&msg[(size_t)cur * FDIM + f], s);
                    s = 0.0f; cur = id[qq];
                }
                s += v[qq];
            }
        }
        // no second barrier: next tile writes the OTHER buffer
    }
    if (cur >= 0) unsafeAtomicAdd(&msg[(size_t)cur * FDIM + f], s);
}

// ---------------------------------------------------------------------------
// Fused node chain (transposed): 3 residuals + outmix + 2 residuals.
// m carried as f32x4[8] per thread (atom fixed per lane, features packed).
// ---------------------------------------------------------------------------
__global__ __launch_bounds__(256) void k_chain(
    const float* __restrict__ msgp, const float* __restrict__ feat,
    const float* __restrict__ u, const ushort_t* __restrict__ wch,
    const float* __restrict__ bri1, const float* __restrict__ bri2,
    const float* __restrict__ bd,
    const float* __restrict__ bra1, const float* __restrict__ bra2,
    float* __restrict__ xout)
{
    __shared__ ushort_t actA[64][136];
    __shared__ ushort_t wlds[128][136];
    const int t = threadIdx.x, lane = t & 63, w = t >> 6;
    const int lrow = lane & 15, kgrp = lane >> 4;
    const int atom = blockIdx.x * 64 + 16 * w + lrow;
    const bool ok = atom < NA;

    f32x4 m[8], h[8], acc[8];
    #pragma unroll
    for (int nf = 0; nf < 8; ++nf)
        m[nf] = ok ? *(const f32x4*)(msgp + (size_t)atom * FDIM + 16 * nf + 4 * kgrp)
                   : (f32x4){0.f, 0.f, 0.f, 0.f};

    // --- 3 interaction residuals ---
    for (int k = 0; k < NRI; ++k) {
        write_act_T(actA, w, lrow, kgrp, m);
        __syncthreads();
        stage_w(wch + (size_t)(2 * k) * 16384, wlds, t);
        __syncthreads();
        gemm_tile_T(actA, wlds, w, lrow, kgrp, bri1 + k * FDIM, acc);
        #pragma unroll
        for (int nf = 0; nf < 8; ++nf) h[nf] = acc[nf];
        write_act_T(actA, w, lrow, kgrp, h);
        __syncthreads();
        stage_w(wch + (size_t)(2 * k + 1) * 16384, wlds, t);
        __syncthreads();
        gemm_tile_T(actA, wlds, w, lrow, kgrp, bri2 + k * FDIM, acc);
        #pragma unroll
        for (int nf = 0; nf < 8; ++nf) m[nf] += acc[nf];
    }

    // --- outmix: m = u*feat + ssp(m)@Wd.T + bd ---
    write_act_T(actA, w, lrow, kgrp, m);
    __syncthreads();
    stage_w(wch + (size_t)6 * 16384, wlds, t);
    __syncthreads();
    gemm_tile_T(actA, wlds, w, lrow, kgrp, bd, acc);
    #pragma unroll
    for (int nf = 0; nf < 8; ++nf) {
        f32x4 fv = ok ? *(const f32x4*)(feat + (size_t)atom * FDIM + 16 * nf + 4 * kgrp)
                      : (f32x4){0.f, 0.f, 0.f, 0.f};
        f32x4 uv = *(const f32x4*)(u + 16 * nf + 4 * kgrp);
        m[nf] = uv * fv + acc[nf];
    }

    // --- 2 atomic residuals ---
    for (int k = 0; k < NRA; ++k) {
        write_act_T(actA, w, lrow, kgrp, m);
        __syncthreads();
        stage_w(wch + (size_t)(7 + 2 * k) * 16384, wlds, t);
        __syncthreads();
        gemm_tile_T(actA, wlds, w, lrow, kgrp, bra1 + k * FDIM, acc);
        #pragma unroll
        for (int nf = 0; nf < 8; ++nf) h[nf] = acc[nf];
        write_act_T(actA, w, lrow, kgrp, h);
        __syncthreads();
        stage_w(wch + (size_t)(8 + 2 * k) * 16384, wlds, t);
        __syncthreads();
        gemm_tile_T(actA, wlds, w, lrow, kgrp, bra2 + k * FDIM, acc);
        #pragma unroll
        for (int nf = 0; nf < 8; ++nf) m[nf] += acc[nf];
    }

    if (ok)
        #pragma unroll
        for (int nf = 0; nf < 8; ++nf)
            *(f32x4*)(xout + (size_t)atom * FDIM + 16 * nf + 4 * kgrp) = m[nf];
}

// ---------------------------------------------------------------------------
extern "C" void kernel_launch(void* const* d_in, const int* in_sizes, int n_in,
                              void* d_out, int out_size, void* d_ws, size_t ws_size,
                              hipStream_t stream)
{
    const float* feat  = (const float*)d_in[0];
    const float* desc  = (const float*)d_in[1];
    const int*   idx_i = (const int*)d_in[2];
    const int*   idx_j = (const int*)d_in[3];
    const float* Wdesc = (const float*)d_in[4];
    const float* Wi    = (const float*)d_in[5];
    const float* bi    = (const float*)d_in[6];
    const float* Wj    = (const float*)d_in[7];
    const float* bj    = (const float*)d_in[8];
    const float* Wri1  = (const float*)d_in[9];
    const float* bri1  = (const float*)d_in[10];
    const float* Wri2  = (const float*)d_in[11];
    const float* bri2  = (const float*)d_in[12];
    const float* Wd    = (const float*)d_in[13];
    const float* bd    = (const float*)d_in[14];
    const float* u     = (const float*)d_in[15];
    const float* Wra1  = (const float*)d_in[16];
    const float* bra1  = (const float*)d_in[17];
    const float* Wra2  = (const float*)d_in[18];
    const float* bra2  = (const float*)d_in[19];

    char* wsp = (char*)d_ws;
    float* msg = (float*)wsp;                             // NA*F f32
    size_t off = (size_t)NA * FDIM * sizeof(float);
    ushort_t* xja = (ushort_t*)(wsp + off);               // NA*F bf16
    off += (size_t)NA * FDIM * sizeof(ushort_t);
    ushort_t* wbf = (ushort_t*)(wsp + off);               // bf16 weights
    off += (((size_t)221184 * sizeof(ushort_t)) + 255) & ~(size_t)255;

    float* xout = (float*)d_out;
    const int nblk64 = (NA + 63) / 64;

    k_wconv<<<dim3(24, 8), 256, 0, stream>>>(Wdesc, Wi, Wj, Wri1, Wri2, Wd, Wra1, Wra2, wbf);
    k_node_pre<<<nblk64, 256, 0, stream>>>(feat, wbf, bi, bj, msg, xja);
    k_edge_fused<<<NE / (64 * ETILES), 256, 0, stream>>>(desc, wbf, idx_i, idx_j, xja, msg);
    k_chain<<<nblk64, 256, 0, stream>>>(msg, feat, u, wbf + 40960,
                                        bri1, bri2, bd, bra1, bra2, xout);
}